// Round 8
// baseline (539.505 us; speedup 1.0000x reference)
//
#include <hip/hip_runtime.h>

#define NB 4
#define NN 4096
#define NE 65536
#define DIN 128
#define DB 64
#define DOUT 128
#define NT 4
#define DCAT 320

#define MT 64               // edges per tile
#define LDH (DOUT + 8)      // 136 elems, 272 B row stride (16-div)
#define NSLICE 128          // persistent blocks per type

typedef __bf16 bf16;
typedef __bf16 bf16x4 __attribute__((ext_vector_type(4)));
typedef __bf16 bf16x8 __attribute__((ext_vector_type(8)));
typedef float floatx4 __attribute__((ext_vector_type(4)));

__device__ __forceinline__ void async16(const void* g, void* l) {
    __builtin_amdgcn_global_load_lds(
        (const __attribute__((address_space(1))) unsigned int*)g,
        (__attribute__((address_space(3))) unsigned int*)l, 16, 0, 0);
}

// ---------------- prep: zero counters, sites fp32->bf16, weight repack W[t][k][n] -> Wt[t][n'][k]
#define NS4 (NB * NN * DIN / 4)      // 524288 float4 groups
#define NA  (NT * 256 * DCAT)        // 327680 WtA elems
#define NB2 (NT * 256 * DOUT)        // 131072 WtB elems
#define NZERO 8208                   // cnt(4+12pad) + deg(4096) + cursor(4096) ints
__global__ void prep_k(const float* __restrict__ sites,
                       const float* __restrict__ W1a, const float* __restrict__ W2a,
                       const float* __restrict__ W1b, const float* __restrict__ W2b,
                       bf16* __restrict__ sitesB,
                       bf16* __restrict__ WtA, bf16* __restrict__ WtB,
                       int* __restrict__ zeroRegion) {
    int i = blockIdx.x * 256 + threadIdx.x;
    if (i < NZERO) zeroRegion[i] = 0;
    if (i < NS4) {
        float4 f = ((const float4*)sites)[i];
        bf16x4 h = { (bf16)f.x, (bf16)f.y, (bf16)f.z, (bf16)f.w };
        ((bf16x4*)sitesB)[i] = h;
    } else if (i < NS4 + NA) {
        int j = i - NS4;
        int k = j % DCAT;
        int n = (j / DCAT) % 256;
        int t = j / (DCAT * 256);
        float w = (n < DOUT) ? W1a[(t * DCAT + k) * DOUT + n]
                             : W2a[(t * DCAT + k) * DOUT + (n - DOUT)];
        WtA[j] = (bf16)w;
    } else {
        int j = i - NS4 - NA;
        int k = j % DOUT;
        int n = (j / DOUT) % 256;
        int t = j / (DOUT * 256);
        float w = (n < DOUT) ? W1b[(t * DOUT + k) * DOUT + n]
                             : W2b[(t * DOUT + k) * DOUT + (n - DOUT)];
        WtB[j] = (bf16)w;
    }
}

// ---------------- bucket edges by type (LDS histogram) + degree count for idx2 CSR
__global__ void bucket_k(const int* __restrict__ uc, const int* __restrict__ idx2,
                         int* __restrict__ cnt, int* __restrict__ deg,
                         int* __restrict__ bucket) {
    __shared__ int h[NT];
    __shared__ int baseo[NT];
    int tid = threadIdx.x;
    if (tid < NT) h[tid] = 0;
    __syncthreads();
    int e = blockIdx.x * 256 + tid;
    int t = uc[e] & 3;
    int lp = atomicAdd(&h[t], 1);         // LDS atomic
    __syncthreads();
    if (tid < NT) baseo[tid] = atomicAdd(&cnt[tid], h[tid]);
    __syncthreads();
    bucket[t * NE + baseo[t] + lp] = e;
    atomicAdd(&deg[idx2[e] & (NN - 1)], 1);
}

// ---------------- exclusive prefix sum deg[4096] -> off[4097]; 256 thr, shuffle scan
__global__ void scan_k(const int* __restrict__ deg, int* __restrict__ off) {
    __shared__ int wsum[4];
    int tid = threadIdx.x;                // 256 threads, each owns 16 elems
    int lane = tid & 63, w = tid >> 6;
    int v[16]; int s = 0;
    #pragma unroll
    for (int j = 0; j < 16; ++j) { v[j] = deg[tid * 16 + j]; s += v[j]; }
    int inc = s;
    #pragma unroll
    for (int d = 1; d < 64; d <<= 1) {
        int x = __shfl_up(inc, d, 64);
        if (lane >= d) inc += x;
    }
    if (lane == 63) wsum[w] = inc;
    __syncthreads();
    int wpre = 0;
    #pragma unroll
    for (int j = 0; j < 4; ++j) wpre += (j < w) ? wsum[j] : 0;
    int excl = wpre + inc - s;
    #pragma unroll
    for (int j = 0; j < 16; ++j) { off[tid * 16 + j] = excl; excl += v[j]; }
    if (tid == 255) off[4096] = excl;
}

// ---------------- fill CSR edge lists
__global__ void fill_k(const int* __restrict__ idx2, const int* __restrict__ off,
                       int* __restrict__ cursor, int* __restrict__ elist) {
    int e = blockIdx.x * 256 + threadIdx.x;
    int n = idx2[e] & (NN - 1);
    int p = atomicAdd(&cursor[n], 1);
    elist[off[n] + p] = e;
}

// ---------------- main: persistent blocks, B-frags register-cached, A via global_load_lds
__launch_bounds__(256, 2)
__global__ void main_k(const bf16* __restrict__ sitesB, const float* __restrict__ bonds,
                       const int* __restrict__ idx1, const int* __restrict__ idx2,
                       const int* __restrict__ cnt, const int* __restrict__ bucket,
                       const bf16* __restrict__ WtA, const bf16* __restrict__ WtB,
                       const float* __restrict__ b1a, const float* __restrict__ b2a,
                       const float* __restrict__ b1b, const float* __restrict__ b2b,
                       const float* __restrict__ Wa1, const float* __restrict__ ba1,
                       const float* __restrict__ Wa2, const float* __restrict__ ba2,
                       bf16* __restrict__ eo) {
    // seg-major A panel: seg s (16B per lane-row) at [s*512 .. s*512+512) elems.
    __shared__ bf16 sVg[32 * 512];   // 32768 B
    __shared__ bf16 sH1[MT * LDH];   // 17408 B
    __shared__ bf16 sH2[MT * LDH];   // 17408 B
    __shared__ int sI1[MT], sI2[MT], sEid[MT];

    const int tid = threadIdx.x;
    const int wv = tid >> 6;
    const int lane = tid & 63;
    const int br = wv >> 1;          // branch (MLP 1/2)
    const int nh = wv & 1;           // column half
    const int lr = lane & 15;
    const int quad = lane >> 4;
    const int lk = quad * 8;
    const int colbase = nh * 64;

    const int bk = blockIdx.x;       // 512 persistent blocks
    const int t = bk & 3;
    const int slice = bk >> 2;       // 0..127
    const int cT = cnt[t];
    const int tpb = (cT + MT - 1) >> 6;   // tiles per batch for this type

    // --- B-fragment warmup: loop-invariant, loaded ONCE, lives in registers.
    //     Compiler cannot sink loads into the loop (they'd re-execute).
    const bf16* WtA_w = WtA + (t * 256 + br * 128 + colbase) * DCAT + lk;
    const bf16* WtB_w = WtB + (t * 256 + br * 128 + colbase) * DOUT + lk;
    bf16x8 B1[10][4];                // 160 VGPRs
    bf16x8 B2[4][4];                 // 64 VGPRs
    #pragma unroll
    for (int ks = 0; ks < 10; ++ks)
        #pragma unroll
        for (int nt = 0; nt < 4; ++nt)
            B1[ks][nt] = *(const bf16x8*)(WtA_w + (nt * 16 + lr) * DCAT + ks * 32);
    #pragma unroll
    for (int ks = 0; ks < 4; ++ks)
        #pragma unroll
        for (int nt = 0; nt < 4; ++nt)
            B2[ks][nt] = *(const bf16x8*)(WtB_w + (nt * 16 + lr) * DOUT + ks * 32);

    bf16* sH = (br == 0) ? sH1 : sH2;
    const float* biasA = ((br == 0) ? b1a : b2a) + t * DOUT;
    const float* biasB = ((br == 0) ? b1b : b2b) + t * DOUT;

    for (int b = 0; b < NB; ++b) {
        for (int ti = slice; ti < tpb; ti += NSLICE) {
            const int base = ti * MT;
            const int nvalid = min(MT, cT - base);

            __syncthreads();   // prev iteration fully done with sEid/sH

            // --- phase 0: edge ids + endpoints
            if (tid < MT) {
                int rr = min(tid, max(nvalid - 1, 0));
                int e = bucket[t * NE + base + rr] & (NE - 1);
                sEid[tid] = e;
                sI1[tid] = idx1[e] & (NN - 1);
                sI2[tid] = idx2[e] & (NN - 1);
            }
            __syncthreads();

            // --- async stage sites panel: wave wv -> segs [wv*8, wv*8+8)
            //     lane = row; LDS dest = uniform base + lane*16 (HW rule)
            {
                int r1 = sI1[lane], r2 = sI2[lane];
                const bf16* bs1 = sitesB + ((size_t)b * NN + r1) * DIN;
                const bf16* bs2 = sitesB + ((size_t)b * NN + r2) * DIN;
                #pragma unroll
                for (int s8 = 0; s8 < 8; ++s8) {
                    int s = wv * 8 + s8;
                    const bf16* src = (s < 16) ? (bs1 + s * 8) : (bs2 + (s - 16) * 8);
                    async16(src, &sVg[s * 512]);
                }
            }
            // --- bond loads (VGPR path; fp32, k-steps 8..9) for this wave's rows
            float4 fb[4][2][2];
            #pragma unroll
            for (int mt = 0; mt < 4; ++mt) {
                const float* pb = bonds + ((size_t)b * NE + sEid[mt * 16 + lr]) * DB + lk;
                fb[mt][0][0] = *(const float4*)pb;
                fb[mt][0][1] = *(const float4*)(pb + 4);
                fb[mt][1][0] = *(const float4*)(pb + 32);
                fb[mt][1][1] = *(const float4*)(pb + 36);
            }
            __syncthreads();   // drains global_load_lds (vmcnt 0) + fb ready

            bf16x8 aB[2][4];
            #pragma unroll
            for (int ks = 0; ks < 2; ++ks)
                #pragma unroll
                for (int mt = 0; mt < 4; ++mt) {
                    float4 f0 = fb[mt][ks][0], f1 = fb[mt][ks][1];
                    aB[ks][mt] = (bf16x8){ (bf16)f0.x, (bf16)f0.y, (bf16)f0.z, (bf16)f0.w,
                                           (bf16)f1.x, (bf16)f1.y, (bf16)f1.z, (bf16)f1.w };
                }

            // --- layer 1 GEMM: A from LDS (ds_read_b128), B from registers
            floatx4 acc[4][4];
            #pragma unroll
            for (int mt = 0; mt < 4; ++mt)
                #pragma unroll
                for (int nt = 0; nt < 4; ++nt)
                    acc[mt][nt] = (floatx4){0.f, 0.f, 0.f, 0.f};

            #pragma unroll
            for (int ks = 0; ks < 10; ++ks) {
                bf16x8 aF[4];
                #pragma unroll
                for (int mt = 0; mt < 4; ++mt) {
                    if (ks < 8)
                        aF[mt] = *(const bf16x8*)(&sVg[(ks * 4 + quad) * 512 + (mt * 16 + lr) * 8]);
                    else
                        aF[mt] = aB[ks - 8][mt];
                }
                #pragma unroll
                for (int nt = 0; nt < 4; ++nt)
                    #pragma unroll
                    for (int mt = 0; mt < 4; ++mt)
                        acc[mt][nt] = __builtin_amdgcn_mfma_f32_16x16x32_bf16(aF[mt], B1[ks][nt], acc[mt][nt], 0, 0, 0);
            }

            // --- bias + lrelu -> bf16 H tile in LDS
            #pragma unroll
            for (int nt = 0; nt < 4; ++nt) {
                int c = colbase + nt * 16 + lr;
                float bias = biasA[c];
                #pragma unroll
                for (int mt = 0; mt < 4; ++mt) {
                    int rbase = mt * 16 + quad * 4;
                    #pragma unroll
                    for (int rg = 0; rg < 4; ++rg) {
                        float v = acc[mt][nt][rg] + bias;
                        v = v > 0.f ? v : 0.01f * v;
                        sH[(rbase + rg) * LDH + c] = (bf16)v;
                    }
                }
            }
            __syncthreads();

            // --- layer 2 GEMM: A = own-branch H from LDS, B from registers
            floatx4 acc2[4][4];
            #pragma unroll
            for (int mt = 0; mt < 4; ++mt)
                #pragma unroll
                for (int nt = 0; nt < 4; ++nt)
                    acc2[mt][nt] = (floatx4){0.f, 0.f, 0.f, 0.f};

            const bf16* sHa = (br == 0) ? sH1 : sH2;
            #pragma unroll
            for (int ks = 0; ks < 4; ++ks) {
                bf16x8 aF[4];
                #pragma unroll
                for (int mt = 0; mt < 4; ++mt)
                    aF[mt] = *(const bf16x8*)(&sHa[(mt * 16 + lr) * LDH + ks * 32 + lk]);
                #pragma unroll
                for (int nt = 0; nt < 4; ++nt)
                    #pragma unroll
                    for (int mt = 0; mt < 4; ++mt)
                        acc2[mt][nt] = __builtin_amdgcn_mfma_f32_16x16x32_bf16(aF[mt], B2[ks][nt], acc2[mt][nt], 0, 0, 0);
            }
            __syncthreads();   // all done READING sH before overwrite

            // --- bias + lrelu -> final per-branch outputs back into sH
            #pragma unroll
            for (int nt = 0; nt < 4; ++nt) {
                int c = colbase + nt * 16 + lr;
                float bias = biasB[c];
                #pragma unroll
                for (int mt = 0; mt < 4; ++mt) {
                    int rbase = mt * 16 + quad * 4;
                    #pragma unroll
                    for (int rg = 0; rg < 4; ++rg) {
                        float v = acc2[mt][nt][rg] + bias;
                        v = v > 0.f ? v : 0.01f * v;
                        sH[(rbase + rg) * LDH + c] = (bf16)v;
                    }
                }
            }
            __syncthreads();

            // --- gate + store g1+g2 per edge (no atomics)
            {
                int m = tid >> 2;
                int q = tid & 3;
                float d1 = 0.f, d2 = 0.f;
                #pragma unroll
                for (int c = 0; c < 32; ++c) {
                    int cc = q * 32 + c;
                    d1 += (float)sH1[m * LDH + cc] * Wa1[cc];
                    d2 += (float)sH2[m * LDH + cc] * Wa2[cc];
                }
                d1 += __shfl_xor(d1, 1); d1 += __shfl_xor(d1, 2);
                d2 += __shfl_xor(d2, 1); d2 += __shfl_xor(d2, 2);
                d1 = fminf(fmaxf(d1 + ba1[0], -30.f), 30.f);
                d2 = fminf(fmaxf(d2 + ba2[0], -30.f), 30.f);
                float s1 = 1.f / (1.f + __expf(-d1));
                float s2 = 1.f / (1.f + __expf(-d2));
                if (m < nvalid) {
                    bf16* dst = eo + ((size_t)b * NE + sEid[m]) * DOUT;
                    #pragma unroll
                    for (int j = 0; j < 4; ++j) {
                        int cc = (q + 4 * j) * 8;
                        bf16x8 w;
                        #pragma unroll
                        for (int c = 0; c < 8; ++c) {
                            int col = cc + c;
                            float v = s1 * (float)sH1[m * LDH + col] + s2 * (float)sH2[m * LDH + col];
                            w[c] = (bf16)v;
                        }
                        *(bf16x8*)(dst + cc) = w;
                    }
                }
            }
        }
    }
}

// ---------------- CSR gather: 1 node/block, 2-way edge-parallel slots + LDS combine
__global__ void gather_k(const bf16* __restrict__ eo, const int* __restrict__ off,
                         const int* __restrict__ elist, float* __restrict__ out) {
    __shared__ float part[128];
    int tid = threadIdx.x;
    int s = tid >> 7;            // slot 0/1
    int c = tid & 127;           // column
    int n = blockIdx.x;
    int b = blockIdx.y;
    int o0 = off[n], o1 = off[n + 1];
    const bf16* eob = eo + (size_t)b * NE * DOUT + c;
    float a0 = 0.f, a1 = 0.f, a2 = 0.f, a3 = 0.f;
    int i = o0 + s;
    for (; i + 6 < o1; i += 8) {
        int e0 = elist[i], e1 = elist[i + 2], e2 = elist[i + 4], e3 = elist[i + 6];
        a0 += (float)eob[(size_t)e0 * DOUT];
        a1 += (float)eob[(size_t)e1 * DOUT];
        a2 += (float)eob[(size_t)e2 * DOUT];
        a3 += (float)eob[(size_t)e3 * DOUT];
    }
    for (; i < o1; i += 2)
        a0 += (float)eob[(size_t)elist[i] * DOUT];
    float tot = (a0 + a1) + (a2 + a3);
    if (s == 0) part[c] = tot;
    __syncthreads();
    if (s == 1) out[((size_t)b * NN + n) * DOUT + c] = part[c] + tot;
}

extern "C" void kernel_launch(void* const* d_in, const int* in_sizes, int n_in,
                              void* d_out, int out_size, void* d_ws, size_t ws_size,
                              hipStream_t stream) {
    const float* sites = (const float*)d_in[0];
    const float* bonds = (const float*)d_in[1];
    const int*   idx1  = (const int*)d_in[2];
    const int*   idx2  = (const int*)d_in[3];
    const int*   uc    = (const int*)d_in[4];
    const float* W1a = (const float*)d_in[5];
    const float* b1a = (const float*)d_in[6];
    const float* W1b = (const float*)d_in[7];
    const float* b1b = (const float*)d_in[8];
    const float* W2a = (const float*)d_in[9];
    const float* b2a = (const float*)d_in[10];
    const float* W2b = (const float*)d_in[11];
    const float* b2b = (const float*)d_in[12];
    const float* Wa1 = (const float*)d_in[13];
    const float* ba1 = (const float*)d_in[14];
    const float* Wa2 = (const float*)d_in[15];
    const float* ba2 = (const float*)d_in[16];
    float* out = (float*)d_out;

    char* ws = (char*)d_ws;
    size_t o_cnt    = 0;
    size_t o_deg    = 64;
    size_t o_cursor = o_deg + NN * 4;
    size_t o_off    = o_cursor + NN * 4;            // 32832B = NZERO*4
    size_t o_bucket = o_off + (NN + 16) * 4;
    size_t o_elist  = o_bucket + (size_t)NT * NE * 4;
    size_t o_wta    = o_elist + (size_t)NE * 4;
    size_t o_wtb    = o_wta + (size_t)NA * 2;
    size_t o_sitesB = o_wtb + (size_t)NB2 * 2;
    size_t o_eo     = o_sitesB + (size_t)NB * NN * DIN * 2;
    size_t need     = o_eo + (size_t)NB * NE * DOUT * 2;   // ~70.2 MiB
    if (ws_size < need) return;   // diagnostic: out stays poisoned

    int*  cnt    = (int*)(ws + o_cnt);
    int*  deg    = (int*)(ws + o_deg);
    int*  cursor = (int*)(ws + o_cursor);
    int*  off    = (int*)(ws + o_off);
    int*  bucket = (int*)(ws + o_bucket);
    int*  elist  = (int*)(ws + o_elist);
    bf16* WtA    = (bf16*)(ws + o_wta);
    bf16* WtB    = (bf16*)(ws + o_wtb);
    bf16* sitesB = (bf16*)(ws + o_sitesB);
    bf16* eo     = (bf16*)(ws + o_eo);

    prep_k<<<(NS4 + NA + NB2) / 256, 256, 0, stream>>>(sites, W1a, W2a, W1b, W2b,
                                                       sitesB, WtA, WtB, (int*)ws);
    bucket_k<<<NE / 256, 256, 0, stream>>>(uc, idx2, cnt, deg, bucket);
    scan_k<<<1, 256, 0, stream>>>(deg, off);
    fill_k<<<NE / 256, 256, 0, stream>>>(idx2, off, cursor, elist);

    main_k<<<NT * NSLICE, 256, 0, stream>>>(    // 512 persistent blocks, 2/CU
        sitesB, bonds, idx1, idx2, cnt, bucket, WtA, WtB,
        b1a, b2a, b1b, b2b, Wa1, ba1, Wa2, ba2, eo);

    gather_k<<<dim3(NN, NB), 256, 0, stream>>>(eo, off, elist, out);
}

// Round 9
// 350.447 us; speedup vs baseline: 1.5395x; 1.5395x over previous
//
#include <hip/hip_runtime.h>

#define NB 4
#define NN 4096
#define NE 65536
#define DIN 128
#define DB 64
#define DOUT 128
#define NT 4
#define DCAT 320

#define MT 64               // edges per tile
#define LDH (DOUT + 8)      // 136 elems, 272 B row stride (16-div)

typedef __bf16 bf16;
typedef __bf16 bf16x4 __attribute__((ext_vector_type(4)));
typedef __bf16 bf16x8 __attribute__((ext_vector_type(8)));
typedef float floatx4 __attribute__((ext_vector_type(4)));

__device__ __forceinline__ void async16(const void* g, void* l) {
    __builtin_amdgcn_global_load_lds(
        (const __attribute__((address_space(1))) unsigned int*)g,
        (__attribute__((address_space(3))) unsigned int*)l, 16, 0, 0);
}

// ---------------- prep: zero counters, sites fp32->bf16, weight repack W[t][k][n] -> Wt[t][n'][k]
#define NS4 (NB * NN * DIN / 4)      // 524288 float4 groups
#define NA  (NT * 256 * DCAT)        // 327680 WtA elems
#define NB2 (NT * 256 * DOUT)        // 131072 WtB elems
#define NZERO 8208                   // cnt(4+12pad) + deg(4096) + cursor(4096) ints
__global__ void prep_k(const float* __restrict__ sites,
                       const float* __restrict__ W1a, const float* __restrict__ W2a,
                       const float* __restrict__ W1b, const float* __restrict__ W2b,
                       bf16* __restrict__ sitesB,
                       bf16* __restrict__ WtA, bf16* __restrict__ WtB,
                       int* __restrict__ zeroRegion) {
    int i = blockIdx.x * 256 + threadIdx.x;
    if (i < NZERO) zeroRegion[i] = 0;
    if (i < NS4) {
        float4 f = ((const float4*)sites)[i];
        bf16x4 h = { (bf16)f.x, (bf16)f.y, (bf16)f.z, (bf16)f.w };
        ((bf16x4*)sitesB)[i] = h;
    } else if (i < NS4 + NA) {
        int j = i - NS4;
        int k = j % DCAT;
        int n = (j / DCAT) % 256;
        int t = j / (DCAT * 256);
        float w = (n < DOUT) ? W1a[(t * DCAT + k) * DOUT + n]
                             : W2a[(t * DCAT + k) * DOUT + (n - DOUT)];
        WtA[j] = (bf16)w;
    } else {
        int j = i - NS4 - NA;
        int k = j % DOUT;
        int n = (j / DOUT) % 256;
        int t = j / (DOUT * 256);
        float w = (n < DOUT) ? W1b[(t * DOUT + k) * DOUT + n]
                             : W2b[(t * DOUT + k) * DOUT + (n - DOUT)];
        WtB[j] = (bf16)w;
    }
}

// ---------------- bucket edges by type (LDS histogram) + degree count for idx2 CSR
__global__ void bucket_k(const int* __restrict__ uc, const int* __restrict__ idx2,
                         int* __restrict__ cnt, int* __restrict__ deg,
                         int* __restrict__ bucket) {
    __shared__ int h[NT];
    __shared__ int baseo[NT];
    int tid = threadIdx.x;
    if (tid < NT) h[tid] = 0;
    __syncthreads();
    int e = blockIdx.x * 256 + tid;
    int t = uc[e] & 3;
    int lp = atomicAdd(&h[t], 1);         // LDS atomic
    __syncthreads();
    if (tid < NT) baseo[tid] = atomicAdd(&cnt[tid], h[tid]);
    __syncthreads();
    bucket[t * NE + baseo[t] + lp] = e;
    atomicAdd(&deg[idx2[e] & (NN - 1)], 1);
}

// ---------------- exclusive prefix sum deg[4096] -> off[4097]; 256 thr, shuffle scan
__global__ void scan_k(const int* __restrict__ deg, int* __restrict__ off) {
    __shared__ int wsum[4];
    int tid = threadIdx.x;                // 256 threads, each owns 16 elems
    int lane = tid & 63, w = tid >> 6;
    int v[16]; int s = 0;
    #pragma unroll
    for (int j = 0; j < 16; ++j) { v[j] = deg[tid * 16 + j]; s += v[j]; }
    int inc = s;
    #pragma unroll
    for (int d = 1; d < 64; d <<= 1) {
        int x = __shfl_up(inc, d, 64);
        if (lane >= d) inc += x;
    }
    if (lane == 63) wsum[w] = inc;
    __syncthreads();
    int wpre = 0;
    #pragma unroll
    for (int j = 0; j < 4; ++j) wpre += (j < w) ? wsum[j] : 0;
    int excl = wpre + inc - s;
    #pragma unroll
    for (int j = 0; j < 16; ++j) { off[tid * 16 + j] = excl; excl += v[j]; }
    if (tid == 255) off[4096] = excl;
}

// ---------------- fill CSR edge lists
__global__ void fill_k(const int* __restrict__ idx2, const int* __restrict__ off,
                       int* __restrict__ cursor, int* __restrict__ elist) {
    int e = blockIdx.x * 256 + threadIdx.x;
    int n = idx2[e] & (NN - 1);
    int p = atomicAdd(&cursor[n], 1);
    elist[off[n] + p] = e;
}

// ---------------- main: m97-style async ks-slab double-buffer for A (sites) and B (weights)
__launch_bounds__(256, 2)
__global__ void main_k(const bf16* __restrict__ sitesB, const float* __restrict__ bonds,
                       const int* __restrict__ idx1, const int* __restrict__ idx2,
                       const int* __restrict__ cnt, const int* __restrict__ bucket,
                       const bf16* __restrict__ WtA, const bf16* __restrict__ WtB,
                       const float* __restrict__ b1a, const float* __restrict__ b2a,
                       const float* __restrict__ b1b, const float* __restrict__ b2b,
                       const float* __restrict__ Wa1, const float* __restrict__ ba1,
                       const float* __restrict__ Wa2, const float* __restrict__ ba2,
                       bf16* __restrict__ eo) {
    // A slab: 64 rows x 32k = 4KB (256 segs of 16B), double-buffered.
    // B slab: 256 cols x 32k = 16KB (1024 segs), double-buffered.
    // Seg-major with XOR swizzle: seg(entity e, quad q) stored at e*4 + (q ^ (e&3)).
    __shared__ bf16 sA[2][2048];     //  8192 B
    __shared__ bf16 sB[2][8192];     // 32768 B
    __shared__ bf16 sH1[MT * LDH];   // 17408 B
    __shared__ bf16 sH2[MT * LDH];   // 17408 B
    __shared__ int sI1[MT], sI2[MT], sEid[MT];

    const int tid = threadIdx.x;

    // --- XCD-pinned decode
    int blk = blockIdx.x;
    int p = blk & 7;
    const int b = p >> 1;
    int flat = ((blk >> 3) << 1) + (p & 1);   // tile index within batch

    // --- map flat tile index -> (type, tile-within-type)
    int c0 = cnt[0], c1 = cnt[1], c2 = cnt[2], c3 = cnt[3];
    int n0 = (c0 + MT - 1) / MT, n1 = (c1 + MT - 1) / MT,
        n2 = (c2 + MT - 1) / MT, n3 = (c3 + MT - 1) / MT;
    int t, ti, cT;
    if (flat < n0)                { t = 0; ti = flat;                cT = c0; }
    else if (flat < n0+n1)        { t = 1; ti = flat - n0;           cT = c1; }
    else if (flat < n0+n1+n2)     { t = 2; ti = flat - n0 - n1;      cT = c2; }
    else if (flat < n0+n1+n2+n3)  { t = 3; ti = flat - n0 - n1 - n2; cT = c3; }
    else return;                  // uniform early-exit before any barrier
    const int base = ti * MT;
    const int nvalid = min(MT, cT - base);

    // --- phase 0: edge ids + endpoints (index-clamped)
    if (tid < MT) {
        int rr = min(tid, max(nvalid - 1, 0));
        int e = bucket[t * NE + base + rr] & (NE - 1);
        sEid[tid] = e;
        sI1[tid] = idx1[e] & (NN - 1);
        sI2[tid] = idx2[e] & (NN - 1);
    }
    __syncthreads();

    const int wv = tid >> 6;
    const int lane = tid & 63;
    const int br = wv >> 1;          // branch
    const int nh = wv & 1;           // column half within branch
    const int lr = lane & 15;
    const int quad = lane >> 4;
    const int lk = quad * 8;
    const int colbase = nh * 64;

    // --- bond fragments (fp32 VGPR path, k-steps 8..9)
    float4 fb[4][2][2];
    #pragma unroll
    for (int mt = 0; mt < 4; ++mt) {
        const float* pb = bonds + ((size_t)b * NE + sEid[mt * 16 + lr]) * DB + lk;
        fb[mt][0][0] = *(const float4*)pb;
        fb[mt][0][1] = *(const float4*)(pb + 4);
        fb[mt][1][0] = *(const float4*)(pb + 32);
        fb[mt][1][1] = *(const float4*)(pb + 36);
    }
    bf16x8 aB[2][4];
    #pragma unroll
    for (int ks = 0; ks < 2; ++ks)
        #pragma unroll
        for (int mt = 0; mt < 4; ++mt) {
            float4 f0 = fb[mt][ks][0], f1 = fb[mt][ks][1];
            aB[ks][mt] = (bf16x8){ (bf16)f0.x, (bf16)f0.y, (bf16)f0.z, (bf16)f0.w,
                                   (bf16)f1.x, (bf16)f1.y, (bf16)f1.z, (bf16)f1.w };
        }

    // --- staging lambdas (per-wave async16; per-lane scattered SOURCE is legal)
    const size_t sbase = (size_t)b * NN;
    auto stageA = [&](int ks, int buf) {           // ks in 0..7
        int d = wv * 64 + lane;
        int row = d >> 2;
        int kseg = (d & 3) ^ (row & 3);            // XOR swizzle
        int r = (ks < 4) ? sI1[row] : sI2[row];
        const bf16* src = sitesB + (sbase + r) * DIN + (ks & 3) * 32 + kseg * 8;
        async16(src, &sA[buf][wv * 512]);
    };
    auto stageB1 = [&](int ks, int buf) {          // WtA, stride DCAT
        #pragma unroll
        for (int j = 0; j < 4; ++j) {
            int d = (j * 4 + wv) * 64 + lane;
            int col = d >> 2;
            int kseg = (d & 3) ^ (col & 3);
            const bf16* src = WtA + (size_t)(t * 256 + col) * DCAT + ks * 32 + kseg * 8;
            async16(src, &sB[buf][(j * 4 + wv) * 512]);
        }
    };
    auto stageB2 = [&](int ks, int buf) {          // WtB, stride DOUT
        #pragma unroll
        for (int j = 0; j < 4; ++j) {
            int d = (j * 4 + wv) * 64 + lane;
            int col = d >> 2;
            int kseg = (d & 3) ^ (col & 3);
            const bf16* src = WtB + (size_t)(t * 256 + col) * DOUT + ks * 32 + kseg * 8;
            async16(src, &sB[buf][(j * 4 + wv) * 512]);
        }
    };

    // --- layer 1 GEMM: 10 ks-slabs, 1 barrier per slab, dbuf
    floatx4 acc[4][4];
    #pragma unroll
    for (int mt = 0; mt < 4; ++mt)
        #pragma unroll
        for (int nt = 0; nt < 4; ++nt)
            acc[mt][nt] = (floatx4){0.f, 0.f, 0.f, 0.f};

    stageA(0, 0);
    stageB1(0, 0);
    #pragma unroll
    for (int ks = 0; ks < 10; ++ks) {
        int buf = ks & 1;
        __syncthreads();               // drain stage(ks); all waves done compute(ks-1)
        if (ks < 9) {
            if (ks + 1 < 8) stageA(ks + 1, buf ^ 1);
            stageB1(ks + 1, buf ^ 1);
        }
        bf16x8 aF[4];
        #pragma unroll
        for (int mt = 0; mt < 4; ++mt) {
            if (ks < 8) {
                int row = mt * 16 + lr;
                aF[mt] = *(const bf16x8*)(&sA[buf][(row * 4 + (quad ^ (lr & 3))) * 8]);
            } else {
                aF[mt] = aB[ks - 8][mt];
            }
        }
        #pragma unroll
        for (int nt = 0; nt < 4; ++nt) {
            int cc = br * 128 + colbase + nt * 16 + lr;
            bf16x8 bF = *(const bf16x8*)(&sB[buf][(cc * 4 + (quad ^ (lr & 3))) * 8]);
            #pragma unroll
            for (int mt = 0; mt < 4; ++mt)
                acc[mt][nt] = __builtin_amdgcn_mfma_f32_16x16x32_bf16(aF[mt], bF, acc[mt][nt], 0, 0, 0);
        }
    }

    // --- bias + lrelu -> bf16 H tile in LDS; prefetch B2 slab 0 (buf0 free: last read was ks=8)
    stageB2(0, 0);
    bf16* sH = (br == 0) ? sH1 : sH2;
    const float* biasA = ((br == 0) ? b1a : b2a) + t * DOUT;
    #pragma unroll
    for (int nt = 0; nt < 4; ++nt) {
        int c = colbase + nt * 16 + lr;
        float bias = biasA[c];
        #pragma unroll
        for (int mt = 0; mt < 4; ++mt) {
            int rbase = mt * 16 + quad * 4;
            #pragma unroll
            for (int rg = 0; rg < 4; ++rg) {
                float v = acc[mt][nt][rg] + bias;
                v = v > 0.f ? v : 0.01f * v;
                sH[(rbase + rg) * LDH + c] = (bf16)v;
            }
        }
    }

    // --- layer 2 GEMM: A = own-branch H from LDS, B2 slabs async dbuf
    floatx4 acc2[4][4];
    #pragma unroll
    for (int mt = 0; mt < 4; ++mt)
        #pragma unroll
        for (int nt = 0; nt < 4; ++nt)
            acc2[mt][nt] = (floatx4){0.f, 0.f, 0.f, 0.f};

    const bf16* sHa = (br == 0) ? sH1 : sH2;
    #pragma unroll
    for (int ks = 0; ks < 4; ++ks) {
        int buf = ks & 1;
        __syncthreads();               // drains stageB2(ks) + sH writes visible (ks=0)
        if (ks < 3) stageB2(ks + 1, buf ^ 1);
        bf16x8 aF[4];
        #pragma unroll
        for (int mt = 0; mt < 4; ++mt)
            aF[mt] = *(const bf16x8*)(&sHa[(mt * 16 + lr) * LDH + ks * 32 + lk]);
        #pragma unroll
        for (int nt = 0; nt < 4; ++nt) {
            int cc = br * 128 + colbase + nt * 16 + lr;
            bf16x8 bF = *(const bf16x8*)(&sB[buf][(cc * 4 + (quad ^ (lr & 3))) * 8]);
            #pragma unroll
            for (int mt = 0; mt < 4; ++mt)
                acc2[mt][nt] = __builtin_amdgcn_mfma_f32_16x16x32_bf16(aF[mt], bF, acc2[mt][nt], 0, 0, 0);
        }
    }
    __syncthreads();   // all waves done READING sH before overwrite

    // --- bias + lrelu -> final per-branch outputs back into sH
    const float* biasB = ((br == 0) ? b1b : b2b) + t * DOUT;
    #pragma unroll
    for (int nt = 0; nt < 4; ++nt) {
        int c = colbase + nt * 16 + lr;
        float bias = biasB[c];
        #pragma unroll
        for (int mt = 0; mt < 4; ++mt) {
            int rbase = mt * 16 + quad * 4;
            #pragma unroll
            for (int rg = 0; rg < 4; ++rg) {
                float v = acc2[mt][nt][rg] + bias;
                v = v > 0.f ? v : 0.01f * v;
                sH[(rbase + rg) * LDH + c] = (bf16)v;
            }
        }
    }
    __syncthreads();

    // --- gate + store g1+g2 per edge (no atomics)
    {
        int m = tid >> 2;
        int q = tid & 3;
        float d1 = 0.f, d2 = 0.f;
        #pragma unroll
        for (int c = 0; c < 32; ++c) {
            int cc = q * 32 + c;
            d1 += (float)sH1[m * LDH + cc] * Wa1[cc];
            d2 += (float)sH2[m * LDH + cc] * Wa2[cc];
        }
        d1 += __shfl_xor(d1, 1); d1 += __shfl_xor(d1, 2);
        d2 += __shfl_xor(d2, 1); d2 += __shfl_xor(d2, 2);
        d1 = fminf(fmaxf(d1 + ba1[0], -30.f), 30.f);
        d2 = fminf(fmaxf(d2 + ba2[0], -30.f), 30.f);
        float s1 = 1.f / (1.f + __expf(-d1));
        float s2 = 1.f / (1.f + __expf(-d2));
        if (m < nvalid) {
            bf16* dst = eo + ((size_t)b * NE + sEid[m]) * DOUT;
            #pragma unroll
            for (int j = 0; j < 4; ++j) {
                int cc = (q + 4 * j) * 8;
                bf16x8 w;
                #pragma unroll
                for (int c = 0; c < 8; ++c) {
                    int col = cc + c;
                    float v = s1 * (float)sH1[m * LDH + col] + s2 * (float)sH2[m * LDH + col];
                    w[c] = (bf16)v;
                }
                *(bf16x8*)(dst + cc) = w;
            }
        }
    }
}

// ---------------- CSR gather: 1 node/block, 2-way edge-parallel slots + LDS combine
__global__ void gather_k(const bf16* __restrict__ eo, const int* __restrict__ off,
                         const int* __restrict__ elist, float* __restrict__ out) {
    __shared__ float part[128];
    int tid = threadIdx.x;
    int s = tid >> 7;            // slot 0/1
    int c = tid & 127;           // column
    int n = blockIdx.x;
    int b = blockIdx.y;
    int o0 = off[n], o1 = off[n + 1];
    const bf16* eob = eo + (size_t)b * NE * DOUT + c;
    float a0 = 0.f, a1 = 0.f, a2 = 0.f, a3 = 0.f;
    int i = o0 + s;
    for (; i + 6 < o1; i += 8) {
        int e0 = elist[i], e1 = elist[i + 2], e2 = elist[i + 4], e3 = elist[i + 6];
        a0 += (float)eob[(size_t)e0 * DOUT];
        a1 += (float)eob[(size_t)e1 * DOUT];
        a2 += (float)eob[(size_t)e2 * DOUT];
        a3 += (float)eob[(size_t)e3 * DOUT];
    }
    for (; i < o1; i += 2)
        a0 += (float)eob[(size_t)elist[i] * DOUT];
    float tot = (a0 + a1) + (a2 + a3);
    if (s == 0) part[c] = tot;
    __syncthreads();
    if (s == 1) out[((size_t)b * NN + n) * DOUT + c] = part[c] + tot;
}

extern "C" void kernel_launch(void* const* d_in, const int* in_sizes, int n_in,
                              void* d_out, int out_size, void* d_ws, size_t ws_size,
                              hipStream_t stream) {
    const float* sites = (const float*)d_in[0];
    const float* bonds = (const float*)d_in[1];
    const int*   idx1  = (const int*)d_in[2];
    const int*   idx2  = (const int*)d_in[3];
    const int*   uc    = (const int*)d_in[4];
    const float* W1a = (const float*)d_in[5];
    const float* b1a = (const float*)d_in[6];
    const float* W1b = (const float*)d_in[7];
    const float* b1b = (const float*)d_in[8];
    const float* W2a = (const float*)d_in[9];
    const float* b2a = (const float*)d_in[10];
    const float* W2b = (const float*)d_in[11];
    const float* b2b = (const float*)d_in[12];
    const float* Wa1 = (const float*)d_in[13];
    const float* ba1 = (const float*)d_in[14];
    const float* Wa2 = (const float*)d_in[15];
    const float* ba2 = (const float*)d_in[16];
    float* out = (float*)d_out;

    char* ws = (char*)d_ws;
    size_t o_cnt    = 0;
    size_t o_deg    = 64;
    size_t o_cursor = o_deg + NN * 4;
    size_t o_off    = o_cursor + NN * 4;            // 32832B = NZERO*4
    size_t o_bucket = o_off + (NN + 16) * 4;
    size_t o_elist  = o_bucket + (size_t)NT * NE * 4;
    size_t o_wta    = o_elist + (size_t)NE * 4;
    size_t o_wtb    = o_wta + (size_t)NA * 2;
    size_t o_sitesB = o_wtb + (size_t)NB2 * 2;
    size_t o_eo     = o_sitesB + (size_t)NB * NN * DIN * 2;
    size_t need     = o_eo + (size_t)NB * NE * DOUT * 2;   // ~70.2 MiB
    if (ws_size < need) return;   // diagnostic: out stays poisoned

    int*  cnt    = (int*)(ws + o_cnt);
    int*  deg    = (int*)(ws + o_deg);
    int*  cursor = (int*)(ws + o_cursor);
    int*  off    = (int*)(ws + o_off);
    int*  bucket = (int*)(ws + o_bucket);
    int*  elist  = (int*)(ws + o_elist);
    bf16* WtA    = (bf16*)(ws + o_wta);
    bf16* WtB    = (bf16*)(ws + o_wtb);
    bf16* sitesB = (bf16*)(ws + o_sitesB);
    bf16* eo     = (bf16*)(ws + o_eo);

    prep_k<<<(NS4 + NA + NB2) / 256, 256, 0, stream>>>(sites, W1a, W2a, W1b, W2b,
                                                       sitesB, WtA, WtB, (int*)ws);
    bucket_k<<<NE / 256, 256, 0, stream>>>(uc, idx2, cnt, deg, bucket);
    scan_k<<<1, 256, 0, stream>>>(deg, off);
    fill_k<<<NE / 256, 256, 0, stream>>>(idx2, off, cursor, elist);

    const int maxTiles = NE / MT + NT;   // 1028 tiles/batch worst case
    main_k<<<maxTiles * NB, 256, 0, stream>>>(
        sitesB, bonds, idx1, idx2, cnt, bucket, WtA, WtB,
        b1a, b2a, b1b, b2b, Wa1, ba1, Wa2, ba2, eo);

    gather_k<<<dim3(NN, NB), 256, 0, stream>>>(eo, off, elist, out);
}

// Round 10
// 326.000 us; speedup vs baseline: 1.6549x; 1.0750x over previous
//
#include <hip/hip_runtime.h>

#define NB 4
#define NN 4096
#define NE 65536
#define DIN 128
#define DB 64
#define DOUT 128
#define NT 4
#define DCAT 320

#define MT 64               // edges per tile
#define LDH (DOUT + 8)      // 136 elems, 272 B row stride (16-div)

typedef __bf16 bf16;
typedef __bf16 bf16x4 __attribute__((ext_vector_type(4)));
typedef __bf16 bf16x8 __attribute__((ext_vector_type(8)));
typedef float floatx4 __attribute__((ext_vector_type(4)));

__device__ __forceinline__ void async16(const void* g, void* l) {
    __builtin_amdgcn_global_load_lds(
        (const __attribute__((address_space(1))) unsigned int*)g,
        (__attribute__((address_space(3))) unsigned int*)l, 16, 0, 0);
}

// ---------------- prep: zero counters, sites fp32->bf16, weight repack W[t][k][n] -> Wt[t][n'][k]
#define NS4 (NB * NN * DIN / 4)      // 524288 float4 groups
#define NA  (NT * 256 * DCAT)        // 327680 WtA elems
#define NB2 (NT * 256 * DOUT)        // 131072 WtB elems
#define NZERO 8208                   // cnt(4+12pad) + deg(4096) + cursor(4096) ints
__global__ void prep_k(const float* __restrict__ sites,
                       const float* __restrict__ W1a, const float* __restrict__ W2a,
                       const float* __restrict__ W1b, const float* __restrict__ W2b,
                       bf16* __restrict__ sitesB,
                       bf16* __restrict__ WtA, bf16* __restrict__ WtB,
                       int* __restrict__ zeroRegion) {
    int i = blockIdx.x * 256 + threadIdx.x;
    if (i < NZERO) zeroRegion[i] = 0;
    if (i < NS4) {
        float4 f = ((const float4*)sites)[i];
        bf16x4 h = { (bf16)f.x, (bf16)f.y, (bf16)f.z, (bf16)f.w };
        ((bf16x4*)sitesB)[i] = h;
    } else if (i < NS4 + NA) {
        int j = i - NS4;
        int k = j % DCAT;
        int n = (j / DCAT) % 256;
        int t = j / (DCAT * 256);
        float w = (n < DOUT) ? W1a[(t * DCAT + k) * DOUT + n]
                             : W2a[(t * DCAT + k) * DOUT + (n - DOUT)];
        WtA[j] = (bf16)w;
    } else {
        int j = i - NS4 - NA;
        int k = j % DOUT;
        int n = (j / DOUT) % 256;
        int t = j / (DOUT * 256);
        float w = (n < DOUT) ? W1b[(t * DOUT + k) * DOUT + n]
                             : W2b[(t * DOUT + k) * DOUT + (n - DOUT)];
        WtB[j] = (bf16)w;
    }
}

// ---------------- bucket edges by type (LDS histogram) + degree count for idx2 CSR
__global__ void bucket_k(const int* __restrict__ uc, const int* __restrict__ idx2,
                         int* __restrict__ cnt, int* __restrict__ deg,
                         int* __restrict__ bucket) {
    __shared__ int h[NT];
    __shared__ int baseo[NT];
    int tid = threadIdx.x;
    if (tid < NT) h[tid] = 0;
    __syncthreads();
    int e = blockIdx.x * 256 + tid;
    int t = uc[e] & 3;
    int lp = atomicAdd(&h[t], 1);         // LDS atomic
    __syncthreads();
    if (tid < NT) baseo[tid] = atomicAdd(&cnt[tid], h[tid]);
    __syncthreads();
    bucket[t * NE + baseo[t] + lp] = e;
    atomicAdd(&deg[idx2[e] & (NN - 1)], 1);
}

// ---------------- exclusive prefix sum deg[4096] -> off[4097]; 256 thr, shuffle scan
__global__ void scan_k(const int* __restrict__ deg, int* __restrict__ off) {
    __shared__ int wsum[4];
    int tid = threadIdx.x;                // 256 threads, each owns 16 elems
    int lane = tid & 63, w = tid >> 6;
    int v[16]; int s = 0;
    #pragma unroll
    for (int j = 0; j < 16; ++j) { v[j] = deg[tid * 16 + j]; s += v[j]; }
    int inc = s;
    #pragma unroll
    for (int d = 1; d < 64; d <<= 1) {
        int x = __shfl_up(inc, d, 64);
        if (lane >= d) inc += x;
    }
    if (lane == 63) wsum[w] = inc;
    __syncthreads();
    int wpre = 0;
    #pragma unroll
    for (int j = 0; j < 4; ++j) wpre += (j < w) ? wsum[j] : 0;
    int excl = wpre + inc - s;
    #pragma unroll
    for (int j = 0; j < 16; ++j) { off[tid * 16 + j] = excl; excl += v[j]; }
    if (tid == 255) off[4096] = excl;
}

// ---------------- fill: perm[e] = CSR position of edge e (off[idx2[e]] + rank)
__global__ void fill_k(const int* __restrict__ idx2, const int* __restrict__ off,
                       int* __restrict__ cursor, int* __restrict__ perm) {
    int e = blockIdx.x * 256 + threadIdx.x;
    int n = idx2[e] & (NN - 1);
    int p = atomicAdd(&cursor[n], 1);
    perm[e] = off[n] + p;
}

// ---------------- main: async ks-slab dbuf for A+B1 (LDS), B2 direct from L2, sH aliased
__launch_bounds__(256, 3)
__global__ void main_k(const bf16* __restrict__ sitesB, const float* __restrict__ bonds,
                       const int* __restrict__ idx1, const int* __restrict__ idx2,
                       const int* __restrict__ cnt, const int* __restrict__ bucket,
                       const int* __restrict__ perm,
                       const bf16* __restrict__ WtA, const bf16* __restrict__ WtB,
                       const float* __restrict__ b1a, const float* __restrict__ b2a,
                       const float* __restrict__ b1b, const float* __restrict__ b2b,
                       const float* __restrict__ Wa1, const float* __restrict__ ba1,
                       const float* __restrict__ Wa2, const float* __restrict__ ba2,
                       bf16* __restrict__ eo) {
    // Union layout (40960 B):
    //   phase GEMM1: sA dbuf [0,8192) + sB dbuf [8192,40960)
    //   phase GEMM2: sH1 [0,17408) + sH2 [17408,34816)   (aliases dead sA/sB)
    __shared__ __align__(16) char smem[40960];
    bf16* sA  = (bf16*)smem;                   // 2 x 2048 elems
    bf16* sB  = (bf16*)(smem + 8192);          // 2 x 8192 elems
    bf16* sH1 = (bf16*)smem;
    bf16* sH2 = (bf16*)(smem + MT * LDH * 2);
    __shared__ int sI1[MT], sI2[MT], sEid[MT], sPrm[MT];

    const int tid = threadIdx.x;

    // --- XCD-pinned decode
    int blk = blockIdx.x;
    int p = blk & 7;
    const int b = p >> 1;
    int flat = ((blk >> 3) << 1) + (p & 1);   // tile index within batch

    // --- map flat tile index -> (type, tile-within-type)
    int c0 = cnt[0], c1 = cnt[1], c2 = cnt[2], c3 = cnt[3];
    int n0 = (c0 + MT - 1) / MT, n1 = (c1 + MT - 1) / MT,
        n2 = (c2 + MT - 1) / MT, n3 = (c3 + MT - 1) / MT;
    int t, ti, cT;
    if (flat < n0)                { t = 0; ti = flat;                cT = c0; }
    else if (flat < n0+n1)        { t = 1; ti = flat - n0;           cT = c1; }
    else if (flat < n0+n1+n2)     { t = 2; ti = flat - n0 - n1;      cT = c2; }
    else if (flat < n0+n1+n2+n3)  { t = 3; ti = flat - n0 - n1 - n2; cT = c3; }
    else return;                  // uniform early-exit before any barrier
    const int base = ti * MT;
    const int nvalid = min(MT, cT - base);

    // --- phase 0: edge ids + endpoints + CSR positions
    if (tid < MT) {
        int rr = min(tid, max(nvalid - 1, 0));
        int e = bucket[t * NE + base + rr] & (NE - 1);
        sEid[tid] = e;
        sPrm[tid] = perm[e] & (NE - 1);
        sI1[tid] = idx1[e] & (NN - 1);
        sI2[tid] = idx2[e] & (NN - 1);
    }
    __syncthreads();

    const int wv = tid >> 6;
    const int lane = tid & 63;
    const int br = wv >> 1;          // branch
    const int nh = wv & 1;           // column half within branch
    const int lr = lane & 15;
    const int quad = lane >> 4;
    const int lk = quad * 8;
    const int colbase = nh * 64;

    // --- bond fragments (fp32 VGPR path, k-steps 8..9) — issued early, long latency
    float4 fb[4][2][2];
    #pragma unroll
    for (int mt = 0; mt < 4; ++mt) {
        const float* pb = bonds + ((size_t)b * NE + sEid[mt * 16 + lr]) * DB + lk;
        fb[mt][0][0] = *(const float4*)pb;
        fb[mt][0][1] = *(const float4*)(pb + 4);
        fb[mt][1][0] = *(const float4*)(pb + 32);
        fb[mt][1][1] = *(const float4*)(pb + 36);
    }
    bf16x8 aB[2][4];
    #pragma unroll
    for (int ks = 0; ks < 2; ++ks)
        #pragma unroll
        for (int mt = 0; mt < 4; ++mt) {
            float4 f0 = fb[mt][ks][0], f1 = fb[mt][ks][1];
            aB[ks][mt] = (bf16x8){ (bf16)f0.x, (bf16)f0.y, (bf16)f0.z, (bf16)f0.w,
                                   (bf16)f1.x, (bf16)f1.y, (bf16)f1.z, (bf16)f1.w };
        }

    // --- staging (async16; scattered per-lane SOURCE legal, LDS dest uniform+lane*16)
    const size_t sbase = (size_t)b * NN;
    auto stageA = [&](int ks, int buf) {           // ks in 0..7
        int d = wv * 64 + lane;
        int row = d >> 2;
        int kseg = (d & 3) ^ (row & 3);            // XOR swizzle
        int r = (ks < 4) ? sI1[row] : sI2[row];
        const bf16* src = sitesB + (sbase + r) * DIN + (ks & 3) * 32 + kseg * 8;
        async16(src, &sA[buf * 2048 + wv * 512]);
    };
    auto stageB1 = [&](int ks, int buf) {          // WtA, stride DCAT
        #pragma unroll
        for (int j = 0; j < 4; ++j) {
            int d = (j * 4 + wv) * 64 + lane;
            int col = d >> 2;
            int kseg = (d & 3) ^ (col & 3);
            const bf16* src = WtA + (size_t)(t * 256 + col) * DCAT + ks * 32 + kseg * 8;
            async16(src, &sB[buf * 8192 + (j * 4 + wv) * 512]);
        }
    };

    // --- layer 1 GEMM: 10 ks-slabs, dbuf, 1 barrier per slab
    floatx4 acc[4][4];
    #pragma unroll
    for (int mt = 0; mt < 4; ++mt)
        #pragma unroll
        for (int nt = 0; nt < 4; ++nt)
            acc[mt][nt] = (floatx4){0.f, 0.f, 0.f, 0.f};

    stageA(0, 0);
    stageB1(0, 0);
    #pragma unroll
    for (int ks = 0; ks < 10; ++ks) {
        int buf = ks & 1;
        __syncthreads();               // drain stage(ks); all waves done compute(ks-1)
        if (ks < 9) {
            if (ks + 1 < 8) stageA(ks + 1, buf ^ 1);
            stageB1(ks + 1, buf ^ 1);
        }
        bf16x8 aF[4];
        #pragma unroll
        for (int mt = 0; mt < 4; ++mt) {
            if (ks < 8) {
                int row = mt * 16 + lr;
                aF[mt] = *(const bf16x8*)(&sA[buf * 2048 + (row * 4 + (quad ^ (lr & 3))) * 8]);
            } else {
                aF[mt] = aB[ks - 8][mt];
            }
        }
        #pragma unroll
        for (int nt = 0; nt < 4; ++nt) {
            int cc = br * 128 + colbase + nt * 16 + lr;
            bf16x8 bF = *(const bf16x8*)(&sB[buf * 8192 + (cc * 4 + (quad ^ (lr & 3))) * 8]);
            #pragma unroll
            for (int mt = 0; mt < 4; ++mt)
                acc[mt][nt] = __builtin_amdgcn_mfma_f32_16x16x32_bf16(aF[mt], bF, acc[mt][nt], 0, 0, 0);
        }
    }
    __syncthreads();   // ALL waves done with sA/sB before sH (aliased) is written

    // --- bias + lrelu -> bf16 H tile in LDS (aliases dead sA/sB region)
    bf16* sH = (br == 0) ? sH1 : sH2;
    const float* biasA = ((br == 0) ? b1a : b2a) + t * DOUT;
    #pragma unroll
    for (int nt = 0; nt < 4; ++nt) {
        int c = colbase + nt * 16 + lr;
        float bias = biasA[c];
        #pragma unroll
        for (int mt = 0; mt < 4; ++mt) {
            int rbase = mt * 16 + quad * 4;
            #pragma unroll
            for (int rg = 0; rg < 4; ++rg) {
                float v = acc[mt][nt][rg] + bias;
                v = v > 0.f ? v : 0.01f * v;
                sH[(rbase + rg) * LDH + c] = (bf16)v;
            }
        }
    }
    __syncthreads();

    // --- layer 2 GEMM: A = own-branch H from LDS, B direct from global (L2-hot, 64KB/type)
    floatx4 acc2[4][4];
    #pragma unroll
    for (int mt = 0; mt < 4; ++mt)
        #pragma unroll
        for (int nt = 0; nt < 4; ++nt)
            acc2[mt][nt] = (floatx4){0.f, 0.f, 0.f, 0.f};

    const bf16* sHa = (br == 0) ? sH1 : sH2;
    const bf16* WtB_w = WtB + (size_t)(t * 256 + br * 128 + colbase) * DOUT + lk;
    #pragma unroll
    for (int ks = 0; ks < 4; ++ks) {
        bf16x8 aF[4];
        #pragma unroll
        for (int mt = 0; mt < 4; ++mt)
            aF[mt] = *(const bf16x8*)(&sHa[(mt * 16 + lr) * LDH + ks * 32 + lk]);
        #pragma unroll
        for (int nt = 0; nt < 4; ++nt) {
            bf16x8 bF = *(const bf16x8*)(&WtB_w[(size_t)(nt * 16 + lr) * DOUT + ks * 32]);
            #pragma unroll
            for (int mt = 0; mt < 4; ++mt)
                acc2[mt][nt] = __builtin_amdgcn_mfma_f32_16x16x32_bf16(aF[mt], bF, acc2[mt][nt], 0, 0, 0);
        }
    }
    __syncthreads();   // all waves done READING sH before overwrite

    // --- bias + lrelu -> final per-branch outputs back into sH
    const float* biasB = ((br == 0) ? b1b : b2b) + t * DOUT;
    #pragma unroll
    for (int nt = 0; nt < 4; ++nt) {
        int c = colbase + nt * 16 + lr;
        float bias = biasB[c];
        #pragma unroll
        for (int mt = 0; mt < 4; ++mt) {
            int rbase = mt * 16 + quad * 4;
            #pragma unroll
            for (int rg = 0; rg < 4; ++rg) {
                float v = acc2[mt][nt][rg] + bias;
                v = v > 0.f ? v : 0.01f * v;
                sH[(rbase + rg) * LDH + c] = (bf16)v;
            }
        }
    }
    __syncthreads();

    // --- gate + store g1+g2 per edge at its CSR slot (contiguous for gather_k)
    {
        int m = tid >> 2;
        int q = tid & 3;
        float d1 = 0.f, d2 = 0.f;
        #pragma unroll
        for (int c = 0; c < 32; ++c) {
            int cc = q * 32 + c;
            d1 += (float)sH1[m * LDH + cc] * Wa1[cc];
            d2 += (float)sH2[m * LDH + cc] * Wa2[cc];
        }
        d1 += __shfl_xor(d1, 1); d1 += __shfl_xor(d1, 2);
        d2 += __shfl_xor(d2, 1); d2 += __shfl_xor(d2, 2);
        d1 = fminf(fmaxf(d1 + ba1[0], -30.f), 30.f);
        d2 = fminf(fmaxf(d2 + ba2[0], -30.f), 30.f);
        float s1 = 1.f / (1.f + __expf(-d1));
        float s2 = 1.f / (1.f + __expf(-d2));
        if (m < nvalid) {
            bf16* dst = eo + ((size_t)b * NE + sPrm[m]) * DOUT;
            #pragma unroll
            for (int j = 0; j < 4; ++j) {
                int cc = (q + 4 * j) * 8;
                bf16x8 w;
                #pragma unroll
                for (int c = 0; c < 8; ++c) {
                    int col = cc + c;
                    float v = s1 * (float)sH1[m * LDH + col] + s2 * (float)sH2[m * LDH + col];
                    w[c] = (bf16)v;
                }
                *(bf16x8*)(dst + cc) = w;
            }
        }
    }
}

// ---------------- CSR gather: eo rows are CSR-ordered -> contiguous streaming reads
__global__ void gather_k(const bf16* __restrict__ eo, const int* __restrict__ off,
                         float* __restrict__ out) {
    __shared__ float part[128];
    int tid = threadIdx.x;
    int s = tid >> 7;            // slot 0/1
    int c = tid & 127;           // column
    int n = blockIdx.x;
    int b = blockIdx.y;
    int o0 = off[n], o1 = off[n + 1];
    const bf16* eob = eo + (size_t)b * NE * DOUT + c;
    float a0 = 0.f, a1 = 0.f, a2 = 0.f, a3 = 0.f;
    int i = o0 + s;
    for (; i + 6 < o1; i += 8) {
        a0 += (float)eob[(size_t)(i)     * DOUT];
        a1 += (float)eob[(size_t)(i + 2) * DOUT];
        a2 += (float)eob[(size_t)(i + 4) * DOUT];
        a3 += (float)eob[(size_t)(i + 6) * DOUT];
    }
    for (; i < o1; i += 2)
        a0 += (float)eob[(size_t)i * DOUT];
    float tot = (a0 + a1) + (a2 + a3);
    if (s == 0) part[c] = tot;
    __syncthreads();
    if (s == 1) out[((size_t)b * NN + n) * DOUT + c] = part[c] + tot;
}

extern "C" void kernel_launch(void* const* d_in, const int* in_sizes, int n_in,
                              void* d_out, int out_size, void* d_ws, size_t ws_size,
                              hipStream_t stream) {
    const float* sites = (const float*)d_in[0];
    const float* bonds = (const float*)d_in[1];
    const int*   idx1  = (const int*)d_in[2];
    const int*   idx2  = (const int*)d_in[3];
    const int*   uc    = (const int*)d_in[4];
    const float* W1a = (const float*)d_in[5];
    const float* b1a = (const float*)d_in[6];
    const float* W1b = (const float*)d_in[7];
    const float* b1b = (const float*)d_in[8];
    const float* W2a = (const float*)d_in[9];
    const float* b2a = (const float*)d_in[10];
    const float* W2b = (const float*)d_in[11];
    const float* b2b = (const float*)d_in[12];
    const float* Wa1 = (const float*)d_in[13];
    const float* ba1 = (const float*)d_in[14];
    const float* Wa2 = (const float*)d_in[15];
    const float* ba2 = (const float*)d_in[16];
    float* out = (float*)d_out;

    char* ws = (char*)d_ws;
    size_t o_cnt    = 0;
    size_t o_deg    = 64;
    size_t o_cursor = o_deg + NN * 4;
    size_t o_off    = o_cursor + NN * 4;            // 32832B = NZERO*4
    size_t o_bucket = o_off + (NN + 16) * 4;
    size_t o_perm   = o_bucket + (size_t)NT * NE * 4;
    size_t o_wta    = o_perm + (size_t)NE * 4;
    size_t o_wtb    = o_wta + (size_t)NA * 2;
    size_t o_sitesB = o_wtb + (size_t)NB2 * 2;
    size_t o_eo     = o_sitesB + (size_t)NB * NN * DIN * 2;
    size_t need     = o_eo + (size_t)NB * NE * DOUT * 2;   // ~70.2 MiB
    if (ws_size < need) return;   // diagnostic: out stays poisoned

    int*  cnt    = (int*)(ws + o_cnt);
    int*  deg    = (int*)(ws + o_deg);
    int*  cursor = (int*)(ws + o_cursor);
    int*  off    = (int*)(ws + o_off);
    int*  bucket = (int*)(ws + o_bucket);
    int*  perm   = (int*)(ws + o_perm);
    bf16* WtA    = (bf16*)(ws + o_wta);
    bf16* WtB    = (bf16*)(ws + o_wtb);
    bf16* sitesB = (bf16*)(ws + o_sitesB);
    bf16* eo     = (bf16*)(ws + o_eo);

    prep_k<<<(NS4 + NA + NB2) / 256, 256, 0, stream>>>(sites, W1a, W2a, W1b, W2b,
                                                       sitesB, WtA, WtB, (int*)ws);
    bucket_k<<<NE / 256, 256, 0, stream>>>(uc, idx2, cnt, deg, bucket);
    scan_k<<<1, 256, 0, stream>>>(deg, off);
    fill_k<<<NE / 256, 256, 0, stream>>>(idx2, off, cursor, perm);

    const int maxTiles = NE / MT + NT;   // 1028 tiles/batch worst case
    main_k<<<maxTiles * NB, 256, 0, stream>>>(
        sitesB, bonds, idx1, idx2, cnt, bucket, perm, WtA, WtB,
        b1a, b2a, b1b, b2b, Wa1, ba1, Wa2, ba2, eo);

    gather_k<<<dim3(NN, NB), 256, 0, stream>>>(eo, off, out);
}